// Round 5
// baseline (363.709 us; speedup 1.0000x reference)
//
#include <hip/hip_runtime.h>

#define NB 32768
#define NCH 8
#define ROWS 32  // rows per block -> 1024 blocks

typedef __bf16 bf16x8 __attribute__((ext_vector_type(8)));
typedef float f32x4 __attribute__((ext_vector_type(4)));
typedef unsigned int u32;
typedef unsigned short u16;
typedef u32 u32x4v __attribute__((ext_vector_type(4)));
typedef u32 u32x2v __attribute__((ext_vector_type(2)));

// bf16 weights, transposed to [n][k]. Order: 0=Wi 1=Wf 2=Wo 3=Wu 4=Ui 5=Uf 6=Uo 7=Uu
__device__ __align__(16) u16 g_wt[8 * 128 * 128];

__device__ __forceinline__ u16 f2bf(float f) {
  u32 u = __builtin_bit_cast(u32, f);
  u32 r = u + 0x7FFFu + ((u >> 16) & 1u);  // RNE
  return (u16)(r >> 16);
}
__device__ __forceinline__ float sigm(float s) {
  return __builtin_amdgcn_rcpf(1.0f + __expf(-s));
}
__device__ __forceinline__ float tanh_f(float v) {
  float e = __expf(2.0f * v);
  return 1.0f - 2.0f * __builtin_amdgcn_rcpf(e + 1.0f);
}

__global__ void prep_weights(const float* __restrict__ Wi, const float* __restrict__ Wf,
                             const float* __restrict__ Wo, const float* __restrict__ Wu,
                             const float* __restrict__ Ui, const float* __restrict__ Uf,
                             const float* __restrict__ Uo, const float* __restrict__ Uu) {
  __shared__ float t[128][129];
  const float* srcs[8] = {Wi, Wf, Wo, Wu, Ui, Uf, Uo, Uu};
  const float* s = srcs[blockIdx.x];
  for (int i = threadIdx.x; i < 16384; i += 256) t[i >> 7][i & 127] = s[i];
  __syncthreads();
  u16* dst = g_wt + blockIdx.x * 16384;
  for (int i = threadIdx.x; i < 16384; i += 256) {
    int n = i >> 7, k = i & 127;
    dst[i] = f2bf(t[k][n]);
  }
}

// A-fragment from swizzled LDS tile [ROWS][128] bf16 (row = 16 x 16B units).
__device__ __forceinline__ bf16x8 ldA(const u32x4v* buf, int row, int ks, int g) {
  u32x4v v = buf[row * 16 + ((ks * 4 + g) ^ (row & 7))];
  return __builtin_bit_cast(bf16x8, v);
}
// B-fragment from global bf16 Wt[n][k]
__device__ __forceinline__ bf16x8 ldB(const u16* wt, int col, int ks, int g) {
  return __builtin_bit_cast(bf16x8, *(const u32x4v*)(wt + col * 128 + ks * 32 + g * 8));
}

// fex swizzle: dword index within [32][128] f32 exchange buffer.
__device__ __forceinline__ int fxsw(int row, int dw) {
  int k = (row >> 2) & 3;
  return row * 128 + (dw ^ (((k & 1) << 4) | ((k >> 1) << 2)));
}

// staging-layout global loads: thread owns rows (tid>>5)+i*8, dwords (tid&31)*4..+3
__device__ __forceinline__ void stage_load(const float* __restrict__ src, int tid, f32x4 hv[4]) {
#pragma unroll
  for (int i = 0; i < 4; ++i) {
    int q = tid + (i << 8);
    hv[i] = *(const f32x4*)(src + (q >> 5) * 128 + (q & 31) * 4);
  }
}
template <bool ACC>
__device__ __forceinline__ void stage_write(u32x4v* buf, int tid, const f32x4 hv[4],
                                            f32x4* htacc) {
  u32x2v* b2 = (u32x2v*)buf;
#pragma unroll
  for (int i = 0; i < 4; ++i) {
    int q = tid + (i << 8);
    int r = q >> 5, c4 = q & 31;
    if (ACC) htacc[i] += hv[i];
    u32x2v p;
    p[0] = (u32)f2bf(hv[i][0]) | ((u32)f2bf(hv[i][1]) << 16);
    p[1] = (u32)f2bf(hv[i][2]) | ((u32)f2bf(hv[i][3]) << 16);
    b2[r * 32 + (c4 ^ ((r & 7) << 1))] = p;
  }
}

// C tile loads directly in MFMA C/D fragment layout (prefetch-friendly).
__device__ __forceinline__ void loadC_frag(const float* __restrict__ Cn, int g, int cl,
                                           int colbase, f32x4 cf[2][2]) {
#pragma unroll
  for (int m = 0; m < 2; ++m)
#pragma unroll
    for (int nf = 0; nf < 2; ++nf) {
      const float* p = Cn + (m * 16 + g * 4) * 128 + colbase + nf * 16 + cl;
#pragma unroll
      for (int r = 0; r < 4; ++r) cf[m][nf][r] = p[r * 128];
    }
}

// acc[2][2] += A(32x128 LDS) @ B(128 x 32 cols of Wt)
__device__ __forceinline__ void gemm_g(const u32x4v* a, const u16* wt, int cl, int g,
                                       int colbase, f32x4 acc[2][2]) {
#pragma unroll
  for (int ks = 0; ks < 4; ++ks) {
    bf16x8 b0 = ldB(wt, colbase + cl, ks, g);
    bf16x8 b1 = ldB(wt, colbase + 16 + cl, ks, g);
#pragma unroll
    for (int m = 0; m < 2; ++m) {
      bf16x8 av = ldA(a, m * 16 + cl, ks, g);
      acc[m][0] = __builtin_amdgcn_mfma_f32_16x16x32_bf16(av, b0, acc[m][0], 0, 0, 0);
      acc[m][1] = __builtin_amdgcn_mfma_f32_16x16x32_bf16(av, b1, acc[m][1], 0, 0, 0);
    }
  }
}

// fragment values -> fex -> staging regs (barrier-protected both sides)
__device__ __forceinline__ void exch(float* fex, const f32x4 fr[2][2], int g, int cl,
                                     int colbase, int tid, f32x4 s4[4]) {
  __syncthreads();  // protect previous fex read
#pragma unroll
  for (int m = 0; m < 2; ++m)
#pragma unroll
    for (int nf = 0; nf < 2; ++nf) {
      int col = colbase + nf * 16 + cl;
#pragma unroll
      for (int r_ = 0; r_ < 4; ++r_)
        fex[fxsw(m * 16 + g * 4 + r_, col)] = fr[m][nf][r_];
    }
  __syncthreads();
  int sr = tid >> 5, sc = (tid & 31) * 4;
#pragma unroll
  for (int i = 0; i < 4; ++i)
    s4[i] = *(const f32x4*)(fex + fxsw(sr + i * 8, sc));
}

__global__ __launch_bounds__(256, 3) void tree_lstm(
    const float* __restrict__ x, const float* __restrict__ h, const float* __restrict__ C,
    const float* __restrict__ b_i, const float* __restrict__ b_f,
    const float* __restrict__ b_o, const float* __restrict__ b_u,
    float* __restrict__ out) {
  __shared__ u32x4v xs[ROWS * 16];     // 8 KB x tile (bf16 swizzled)
  __shared__ u32x4v hb[2][ROWS * 16];  // 16 KB child h double buffer
  __shared__ float fex[ROWS * 128];    // 16 KB exchange (epilogue only)

  const int tid = threadIdx.x;
  const int lane = tid & 63;
  const int wv = tid >> 6;
  const int colbase = wv * 32;
  const int row0 = blockIdx.x * ROWS;
  const int g = lane >> 4;
  const int cl = lane & 15;
  const int sr = tid >> 5;
  const int sc = (tid & 31) * 4;
  const f32x4 fz = {0.f, 0.f, 0.f, 0.f};

  // ---- prologue: get memory moving immediately ----
  f32x4 xv[4];
  stage_load(x + (size_t)row0 * 128, tid, xv);
  f32x4 cf[2][2][2];  // ping-pong C fragment prefetch
  loadC_frag(C + (size_t)row0 * 128, g, cl, colbase, cf[0]);
  f32x4 hv[4];
  stage_load(h + (size_t)row0 * 128, tid, hv);

  const float bf0 = b_f[colbase + cl], bf1 = b_f[colbase + 16 + cl];
  const float bi0 = b_i[colbase + cl], bi1 = b_i[colbase + 16 + cl];
  const float bo0 = b_o[colbase + cl], bo1 = b_o[colbase + 16 + cl];
  const float bu0 = b_u[colbase + cl], bu1 = b_u[colbase + 16 + cl];

  stage_write<false>(xs, tid, xv, nullptr);
  __syncthreads();

  f32x4 htacc[4] = {fz, fz, fz, fz};
  stage_write<true>(hb[0], tid, hv, htacc);  // child 0 -> LDS
  stage_load(h + ((size_t)1 * NB + row0) * 128, tid, hv);  // child 1 in flight

  f32x4 afx[2][2];
#pragma unroll
  for (int m = 0; m < 2; ++m) { afx[m][0] = fz; afx[m][1] = fz; }
  gemm_g(xs, g_wt + 1 * 16384, cl, g, colbase, afx);
  __syncthreads();  // hb[0] visible

  f32x4 accc[2][2];
#pragma unroll
  for (int m = 0; m < 2; ++m) { accc[m][0] = fz; accc[m][1] = fz; }

  // ---- child loop: 1 barrier / child, memory always in flight ----
#pragma unroll
  for (int n = 0; n < NCH; ++n) {
    if (n + 1 < NCH)  // C[n+1] fragments: consumed next iteration
      loadC_frag(C + ((size_t)(n + 1) * NB + row0) * 128, g, cl, colbase, cf[(n + 1) & 1]);
    if (n + 1 < NCH)  // commit h[n+1] (loads issued last iter) to LDS
      stage_write<true>(hb[(n + 1) & 1], tid, hv, htacc);
    if (n + 2 < NCH)  // h[n+2] loads in flight
      stage_load(h + ((size_t)(n + 2) * NB + row0) * 128, tid, hv);

    f32x4 f[2][2];
#pragma unroll
    for (int m = 0; m < 2; ++m) { f[m][0] = fz; f[m][1] = fz; }
    gemm_g(hb[n & 1], g_wt + 5 * 16384, cl, g, colbase, f);

    // fused epilogue in fragment layout: accc += sigmoid(f + afx + b_f) * C[n]
#pragma unroll
    for (int m = 0; m < 2; ++m)
#pragma unroll
      for (int nf = 0; nf < 2; ++nf) {
        float bfv = nf ? bf1 : bf0;
#pragma unroll
        for (int r = 0; r < 4; ++r)
          accc[m][nf][r] += sigm(f[m][nf][r] + afx[m][nf][r] + bfv) * cf[n & 1][m][nf][r];
      }
    __syncthreads();
  }

  // ---- h_tilde -> bf16 swizzled LDS (hb[0] free now) ----
  {
    u32x2v* b2 = (u32x2v*)hb[0];
#pragma unroll
    for (int i = 0; i < 4; ++i) {
      int q = tid + (i << 8);
      int r = q >> 5, c4 = q & 31;
      u32x2v p;
      p[0] = (u32)f2bf(htacc[i][0]) | ((u32)f2bf(htacc[i][1]) << 16);
      p[1] = (u32)f2bf(htacc[i][2]) | ((u32)f2bf(htacc[i][3]) << 16);
      b2[r * 32 + (c4 ^ ((r & 7) << 1))] = p;
    }
  }
  __syncthreads();
  const u32x4v* ht = hb[0];

  f32x4 pre[2][2];

  // u = tanh(x@Wu + ht@Uu + bu)  (fragment layout)
#pragma unroll
  for (int m = 0; m < 2; ++m) { pre[m][0] = fz; pre[m][1] = fz; }
  gemm_g(xs, g_wt + 3 * 16384, cl, g, colbase, pre);
  gemm_g(ht, g_wt + 7 * 16384, cl, g, colbase, pre);
  f32x4 uF[2][2];
#pragma unroll
  for (int m = 0; m < 2; ++m)
#pragma unroll
    for (int nf = 0; nf < 2; ++nf) {
      float bv = nf ? bu1 : bu0;
#pragma unroll
      for (int r = 0; r < 4; ++r) uF[m][nf][r] = tanh_f(pre[m][nf][r] + bv);
    }

  // i gate -> c = i*u + accc ; keep tanh(c) in fragment layout
#pragma unroll
  for (int m = 0; m < 2; ++m) { pre[m][0] = fz; pre[m][1] = fz; }
  gemm_g(xs, g_wt + 0 * 16384, cl, g, colbase, pre);
  gemm_g(ht, g_wt + 4 * 16384, cl, g, colbase, pre);
  f32x4 cF[2][2], tF[2][2];
#pragma unroll
  for (int m = 0; m < 2; ++m)
#pragma unroll
    for (int nf = 0; nf < 2; ++nf) {
      float bv = nf ? bi1 : bi0;
#pragma unroll
      for (int r = 0; r < 4; ++r) {
        float cv = sigm(pre[m][nf][r] + bv) * uF[m][nf][r] + accc[m][nf][r];
        cF[m][nf][r] = cv;
        tF[m][nf][r] = tanh_f(cv);
      }
    }

  // store c_j coalesced via exchange
  f32x4 s4[4];
  exch(fex, cF, g, cl, colbase, tid, s4);
  float* outc = out + (size_t)NB * 128;
#pragma unroll
  for (int i = 0; i < 4; ++i)
    *(f32x4*)(outc + (size_t)(row0 + sr + i * 8) * 128 + sc) = s4[i];

  // o gate -> h_j
#pragma unroll
  for (int m = 0; m < 2; ++m) { pre[m][0] = fz; pre[m][1] = fz; }
  gemm_g(xs, g_wt + 2 * 16384, cl, g, colbase, pre);
  gemm_g(ht, g_wt + 6 * 16384, cl, g, colbase, pre);
  f32x4 hF[2][2];
#pragma unroll
  for (int m = 0; m < 2; ++m)
#pragma unroll
    for (int nf = 0; nf < 2; ++nf) {
      float bv = nf ? bo1 : bo0;
#pragma unroll
      for (int r = 0; r < 4; ++r)
        hF[m][nf][r] = sigm(pre[m][nf][r] + bv) * tF[m][nf][r];
    }
  exch(fex, hF, g, cl, colbase, tid, s4);
#pragma unroll
  for (int i = 0; i < 4; ++i)
    *(f32x4*)(out + (size_t)(row0 + sr + i * 8) * 128 + sc) = s4[i];
}

extern "C" void kernel_launch(void* const* d_in, const int* in_sizes, int n_in,
                              void* d_out, int out_size, void* d_ws, size_t ws_size,
                              hipStream_t stream) {
  (void)in_sizes; (void)n_in; (void)out_size; (void)d_ws; (void)ws_size;
  const float* x = (const float*)d_in[0];
  const float* h = (const float*)d_in[1];
  const float* C = (const float*)d_in[2];

  prep_weights<<<8, 256, 0, stream>>>(
      (const float*)d_in[3], (const float*)d_in[4], (const float*)d_in[5],
      (const float*)d_in[6], (const float*)d_in[7], (const float*)d_in[8],
      (const float*)d_in[9], (const float*)d_in[10]);

  tree_lstm<<<NB / ROWS, 256, 0, stream>>>(
      x, h, C,
      (const float*)d_in[11], (const float*)d_in[12],
      (const float*)d_in[13], (const float*)d_in[14],
      (float*)d_out);
}

// Round 6
// 152.753 us; speedup vs baseline: 2.3810x; 2.3810x over previous
//
#include <hip/hip_runtime.h>

#define NB 32768
#define NCH 8
#define ROWS 32  // rows per block -> 1024 blocks

typedef __bf16 bf16x8 __attribute__((ext_vector_type(8)));
typedef float f32x4 __attribute__((ext_vector_type(4)));
typedef unsigned int u32;
typedef unsigned short u16;
typedef u32 u32x4v __attribute__((ext_vector_type(4)));
typedef u32 u32x2v __attribute__((ext_vector_type(2)));

// bf16 weights, transposed to [n][k]. Order: 0=Wi 1=Wf 2=Wo 3=Wu 4=Ui 5=Uf 6=Uo 7=Uu
__device__ __align__(16) u16 g_wt[8 * 128 * 128];

__device__ __forceinline__ u16 f2bf(float f) {
  u32 u = __builtin_bit_cast(u32, f);
  u32 r = u + 0x7FFFu + ((u >> 16) & 1u);  // RNE
  return (u16)(r >> 16);
}
__device__ __forceinline__ float sigm(float s) {
  return __builtin_amdgcn_rcpf(1.0f + __expf(-s));
}
__device__ __forceinline__ float tanh_f(float v) {
  float e = __expf(2.0f * v);
  return 1.0f - 2.0f * __builtin_amdgcn_rcpf(e + 1.0f);
}

__global__ void prep_weights(const float* __restrict__ Wi, const float* __restrict__ Wf,
                             const float* __restrict__ Wo, const float* __restrict__ Wu,
                             const float* __restrict__ Ui, const float* __restrict__ Uf,
                             const float* __restrict__ Uo, const float* __restrict__ Uu) {
  __shared__ float t[128][129];
  const float* srcs[8] = {Wi, Wf, Wo, Wu, Ui, Uf, Uo, Uu};
  const float* s = srcs[blockIdx.x];
  for (int i = threadIdx.x; i < 16384; i += 256) t[i >> 7][i & 127] = s[i];
  __syncthreads();
  u16* dst = g_wt + blockIdx.x * 16384;
  for (int i = threadIdx.x; i < 16384; i += 256) {
    int n = i >> 7, k = i & 127;
    dst[i] = f2bf(t[k][n]);
  }
}

// ---------- bf16 swizzled tile (x, h_tilde) : same as R4 ----------
__device__ __forceinline__ bf16x8 ldA(const u32x4v* buf, int row, int ks, int g) {
  u32x4v v = buf[row * 16 + ((ks * 4 + g) ^ (row & 7))];
  return __builtin_bit_cast(bf16x8, v);
}
__device__ __forceinline__ bf16x8 ldB(const u16* wt, int col, int ks, int g) {
  return __builtin_bit_cast(bf16x8, *(const u32x4v*)(wt + col * 128 + ks * 32 + g * 8));
}

__device__ __forceinline__ void stage_load(const float* __restrict__ src, int tid, f32x4 v[4]) {
#pragma unroll
  for (int i = 0; i < 4; ++i) {
    int q = tid + (i << 8);
    v[i] = *(const f32x4*)(src + (q >> 5) * 128 + (q & 31) * 4);
  }
}
__device__ __forceinline__ void stage_write(u32x4v* buf, int tid, const f32x4 v[4]) {
  u32x2v* b2 = (u32x2v*)buf;
#pragma unroll
  for (int i = 0; i < 4; ++i) {
    int q = tid + (i << 8);
    int r = q >> 5, c4 = q & 31;
    u32x2v p;
    p[0] = (u32)f2bf(v[i][0]) | ((u32)f2bf(v[i][1]) << 16);
    p[1] = (u32)f2bf(v[i][2]) | ((u32)f2bf(v[i][3]) << 16);
    b2[r * 32 + (c4 ^ ((r & 7) << 1))] = p;
  }
}

// ---------- f32 tile staged by global_load_lds with pre-swizzled source ----------
// LDS physical 16B-block (row, pb) holds global logical block (row, pb ^ (row&7)).
__device__ __forceinline__ void stage_gll(const float* __restrict__ src, float* dst,
                                          int lane, int wv) {
#pragma unroll
  for (int i = 0; i < 4; ++i) {
    int r0 = wv * 8 + i * 2;               // 2 rows per 1KB instr, wave owns 8 rows
    int row = r0 + (lane >> 5);
    const float* g = src + row * 128 + (((lane & 31) ^ (row & 7)) << 2);
    __builtin_amdgcn_global_load_lds(
        (const __attribute__((address_space(1))) void*)g,
        (__attribute__((address_space(3))) void*)(dst + r0 * 128), 16, 0, 0);
  }
}
// A-fragment from f32 swizzled tile, convert to bf16 on read.
__device__ __forceinline__ bf16x8 ldAf(const float* buf, int row, int ks, int g) {
  int s = row & 7;
  const float* base = buf + row * 128 + ks * 32;
  f32x4 lo = *(const f32x4*)(base + (((g * 2) ^ s) << 2));
  f32x4 hi = *(const f32x4*)(base + (((g * 2 + 1) ^ s) << 2));
  bf16x8 r;
  r[0] = (__bf16)lo[0]; r[1] = (__bf16)lo[1]; r[2] = (__bf16)lo[2]; r[3] = (__bf16)lo[3];
  r[4] = (__bf16)hi[0]; r[5] = (__bf16)hi[1]; r[6] = (__bf16)hi[2]; r[7] = (__bf16)hi[3];
  return r;
}

// C tile loads in MFMA C/D fragment layout.
__device__ __forceinline__ void loadC_frag(const float* __restrict__ Cn, int g, int cl,
                                           int cb, f32x4 cf[2][2]) {
#pragma unroll
  for (int m = 0; m < 2; ++m)
#pragma unroll
    for (int nf = 0; nf < 2; ++nf) {
      const float* p = Cn + (m * 16 + g * 4) * 128 + cb + nf * 16 + cl;
#pragma unroll
      for (int r = 0; r < 4; ++r) cf[m][nf][r] = p[r * 128];
    }
}

// acc[2][2] += A(32x128, bf16 LDS) @ B(128 x 32 cols)
__device__ __forceinline__ void gemm_g(const u32x4v* a, const u16* wt, int cl, int g,
                                       int cb, f32x4 acc[2][2]) {
#pragma unroll
  for (int ks = 0; ks < 4; ++ks) {
    bf16x8 b0 = ldB(wt, cb + cl, ks, g);
    bf16x8 b1 = ldB(wt, cb + 16 + cl, ks, g);
    bf16x8 a0 = ldA(a, cl, ks, g);
    bf16x8 a1 = ldA(a, 16 + cl, ks, g);
    acc[0][0] = __builtin_amdgcn_mfma_f32_16x16x32_bf16(a0, b0, acc[0][0], 0, 0, 0);
    acc[0][1] = __builtin_amdgcn_mfma_f32_16x16x32_bf16(a0, b1, acc[0][1], 0, 0, 0);
    acc[1][0] = __builtin_amdgcn_mfma_f32_16x16x32_bf16(a1, b0, acc[1][0], 0, 0, 0);
    acc[1][1] = __builtin_amdgcn_mfma_f32_16x16x32_bf16(a1, b1, acc[1][1], 0, 0, 0);
  }
}
// same but A from f32 gll tile
__device__ __forceinline__ void gemm_gf(const float* a, const u16* wt, int cl, int g,
                                        int cb, f32x4 acc[2][2]) {
#pragma unroll
  for (int ks = 0; ks < 4; ++ks) {
    bf16x8 b0 = ldB(wt, cb + cl, ks, g);
    bf16x8 b1 = ldB(wt, cb + 16 + cl, ks, g);
    bf16x8 a0 = ldAf(a, cl, ks, g);
    bf16x8 a1 = ldAf(a, 16 + cl, ks, g);
    acc[0][0] = __builtin_amdgcn_mfma_f32_16x16x32_bf16(a0, b0, acc[0][0], 0, 0, 0);
    acc[0][1] = __builtin_amdgcn_mfma_f32_16x16x32_bf16(a0, b1, acc[0][1], 0, 0, 0);
    acc[1][0] = __builtin_amdgcn_mfma_f32_16x16x32_bf16(a1, b0, acc[1][0], 0, 0, 0);
    acc[1][1] = __builtin_amdgcn_mfma_f32_16x16x32_bf16(a1, b1, acc[1][1], 0, 0, 0);
  }
}

// fex swizzle for the end-only fragment->staging exchange
__device__ __forceinline__ int fxsw(int row, int dw) {
  int k = (row >> 2) & 3;
  return row * 128 + (dw ^ (((k & 1) << 4) | ((k >> 1) << 2)));
}
__device__ __forceinline__ void exch(float* ex, const f32x4 fr[2][2], int g, int cl,
                                     int cb, int tid, f32x4 s4[4]) {
  __syncthreads();
#pragma unroll
  for (int m = 0; m < 2; ++m)
#pragma unroll
    for (int nf = 0; nf < 2; ++nf) {
      int col = cb + nf * 16 + cl;
#pragma unroll
      for (int r_ = 0; r_ < 4; ++r_)
        ex[fxsw(m * 16 + g * 4 + r_, col)] = fr[m][nf][r_];
    }
  __syncthreads();
  int sr = tid >> 5, sc = (tid & 31) * 4;
#pragma unroll
  for (int i = 0; i < 4; ++i)
    s4[i] = *(const f32x4*)(ex + fxsw(sr + i * 8, sc));
}

__global__ __launch_bounds__(256) void tree_lstm(
    const float* __restrict__ x, const float* __restrict__ h, const float* __restrict__ C,
    const float* __restrict__ b_i, const float* __restrict__ b_f,
    const float* __restrict__ b_o, const float* __restrict__ b_u,
    float* __restrict__ out) {
  __shared__ float hbf[2][ROWS * 128];  // 2 x 16KB f32, gll double buffer
  __shared__ u32x4v xs[ROWS * 16];      // 8KB bf16 swizzled x tile

  const int tid = threadIdx.x;
  const int lane = tid & 63;
  const int wv = tid >> 6;
  const int cb = wv * 32;
  const int row0 = blockIdx.x * ROWS;
  const int g = lane >> 4;
  const int cl = lane & 15;
  const int sr = tid >> 5;
  const int sc = (tid & 31) * 4;
  const f32x4 fz = {0.f, 0.f, 0.f, 0.f};

  // ---- prologue ----
  stage_gll(h + (size_t)row0 * 128, hbf[0], lane, wv);  // child 0, unsinkable
  f32x4 xv[4];
  stage_load(x + (size_t)row0 * 128, tid, xv);

  const float bf0 = b_f[cb + cl], bf1 = b_f[cb + 16 + cl];
  const float bi0 = b_i[cb + cl], bi1 = b_i[cb + 16 + cl];
  const float bo0 = b_o[cb + cl], bo1 = b_o[cb + 16 + cl];
  const float bu0 = b_u[cb + cl], bu1 = b_u[cb + 16 + cl];

  stage_write(xs, tid, xv);
  __syncthreads();  // xs ready; gll child-0 drained (vmcnt0)

  f32x4 afx[2][2];
#pragma unroll
  for (int m = 0; m < 2; ++m) { afx[m][0] = fz; afx[m][1] = fz; }
  gemm_g(xs, g_wt + 1 * 16384, cl, g, cb, afx);

  f32x4 accc[2][2];
#pragma unroll
  for (int m = 0; m < 2; ++m) { accc[m][0] = fz; accc[m][1] = fz; }
  f32x4 htacc[4] = {fz, fz, fz, fz};

  // ---- child loop: 1 barrier/child ----
  for (int n = 0; n < NCH; ++n) {
    if (n + 1 < NCH)  // next child straight to LDS, zero VGPR cost
      stage_gll(h + ((size_t)(n + 1) * NB + row0) * 128, hbf[(n + 1) & 1], lane, wv);
    f32x4 cr[2][2];
    loadC_frag(C + ((size_t)n * NB + row0) * 128, g, cl, cb, cr);
    __builtin_amdgcn_sched_barrier(0);  // pin gll + C issue above the gemm

    const float* cur = hbf[n & 1];
    f32x4 f[2][2];
#pragma unroll
    for (int m = 0; m < 2; ++m) { f[m][0] = fz; f[m][1] = fz; }
    gemm_gf(cur, g_wt + 5 * 16384, cl, g, cb, f);

    // h_tilde partial sums from the staged tile (conflict-free b128 reads)
#pragma unroll
    for (int i = 0; i < 4; ++i) {
      int q = tid + (i << 8);
      int r = q >> 5, c4 = q & 31;
      htacc[i] += *(const f32x4*)(cur + r * 128 + ((c4 ^ (r & 7)) << 2));
    }

    // fused f-gate epilogue in fragment layout
#pragma unroll
    for (int m = 0; m < 2; ++m)
#pragma unroll
      for (int nf = 0; nf < 2; ++nf) {
        float bfv = nf ? bf1 : bf0;
#pragma unroll
        for (int r = 0; r < 4; ++r)
          accc[m][nf][r] += sigm(f[m][nf][r] + afx[m][nf][r] + bfv) * cr[m][nf][r];
      }
    __syncthreads();  // tile n+1 staged & visible
  }

  // ---- h_tilde -> bf16 swizzled tile in hbf[0] (free after loop) ----
  {
    u32x2v* b2 = (u32x2v*)hbf[0];
#pragma unroll
    for (int i = 0; i < 4; ++i) {
      int q = tid + (i << 8);
      int r = q >> 5, c4 = q & 31;
      u32x2v p;
      p[0] = (u32)f2bf(htacc[i][0]) | ((u32)f2bf(htacc[i][1]) << 16);
      p[1] = (u32)f2bf(htacc[i][2]) | ((u32)f2bf(htacc[i][3]) << 16);
      b2[r * 32 + (c4 ^ ((r & 7) << 1))] = p;
    }
  }
  __syncthreads();
  const u32x4v* ht = (const u32x4v*)hbf[0];
  float* ex = hbf[1];  // exchange buffer

  f32x4 pre[2][2], s4[4];

  // u = tanh(x@Wu + ht@Uu + bu)
#pragma unroll
  for (int m = 0; m < 2; ++m) { pre[m][0] = fz; pre[m][1] = fz; }
  gemm_g(xs, g_wt + 3 * 16384, cl, g, cb, pre);
  gemm_g(ht, g_wt + 7 * 16384, cl, g, cb, pre);
  f32x4 uF[2][2];
#pragma unroll
  for (int m = 0; m < 2; ++m)
#pragma unroll
    for (int nf = 0; nf < 2; ++nf) {
      float bv = nf ? bu1 : bu0;
#pragma unroll
      for (int r = 0; r < 4; ++r) uF[m][nf][r] = tanh_f(pre[m][nf][r] + bv);
    }

  // i gate -> c = i*u + accc
#pragma unroll
  for (int m = 0; m < 2; ++m) { pre[m][0] = fz; pre[m][1] = fz; }
  gemm_g(xs, g_wt + 0 * 16384, cl, g, cb, pre);
  gemm_g(ht, g_wt + 4 * 16384, cl, g, cb, pre);
  f32x4 cF[2][2], tF[2][2];
#pragma unroll
  for (int m = 0; m < 2; ++m)
#pragma unroll
    for (int nf = 0; nf < 2; ++nf) {
      float bv = nf ? bi1 : bi0;
#pragma unroll
      for (int r = 0; r < 4; ++r) {
        float cv = sigm(pre[m][nf][r] + bv) * uF[m][nf][r] + accc[m][nf][r];
        cF[m][nf][r] = cv;
        tF[m][nf][r] = tanh_f(cv);
      }
    }
  exch(ex, cF, g, cl, cb, tid, s4);
  float* outc = out + (size_t)NB * 128;
#pragma unroll
  for (int i = 0; i < 4; ++i)
    *(f32x4*)(outc + (size_t)(row0 + sr + i * 8) * 128 + sc) = s4[i];

  // o gate -> h_j
#pragma unroll
  for (int m = 0; m < 2; ++m) { pre[m][0] = fz; pre[m][1] = fz; }
  gemm_g(xs, g_wt + 2 * 16384, cl, g, cb, pre);
  gemm_g(ht, g_wt + 6 * 16384, cl, g, cb, pre);
  f32x4 hF[2][2];
#pragma unroll
  for (int m = 0; m < 2; ++m)
#pragma unroll
    for (int nf = 0; nf < 2; ++nf) {
      float bv = nf ? bo1 : bo0;
#pragma unroll
      for (int r = 0; r < 4; ++r)
        hF[m][nf][r] = sigm(pre[m][nf][r] + bv) * tF[m][nf][r];
    }
  exch(ex, hF, g, cl, cb, tid, s4);
#pragma unroll
  for (int i = 0; i < 4; ++i)
    *(f32x4*)(out + (size_t)(row0 + sr + i * 8) * 128 + sc) = s4[i];
}

extern "C" void kernel_launch(void* const* d_in, const int* in_sizes, int n_in,
                              void* d_out, int out_size, void* d_ws, size_t ws_size,
                              hipStream_t stream) {
  (void)in_sizes; (void)n_in; (void)out_size; (void)d_ws; (void)ws_size;
  const float* x = (const float*)d_in[0];
  const float* h = (const float*)d_in[1];
  const float* C = (const float*)d_in[2];

  prep_weights<<<8, 256, 0, stream>>>(
      (const float*)d_in[3], (const float*)d_in[4], (const float*)d_in[5],
      (const float*)d_in[6], (const float*)d_in[7], (const float*)d_in[8],
      (const float*)d_in[9], (const float*)d_in[10]);

  tree_lstm<<<NB / ROWS, 256, 0, stream>>>(
      x, h, C,
      (const float*)d_in[11], (const float*)d_in[12],
      (const float*)d_in[13], (const float*)d_in[14],
      (float*)d_out);
}